// Round 7
// baseline (363.616 us; speedup 1.0000x reference)
//
#include <hip/hip_runtime.h>
#include <hip/hip_bf16.h>
#include <math.h>

typedef __bf16 bf16;
typedef unsigned char u8;
typedef __bf16 bf16x8 __attribute__((ext_vector_type(8)));
typedef float f32x4 __attribute__((ext_vector_type(4)));

#define BB 64
#define NN 256
#define DD 768
#define MM (BB*NN)           // 16384
#define KP 1024              // agg phase-1 K (4 relations * 256); fp8 row stride (bytes)
#define WSZ (DD*DD)          // 589824
#define TL 144               // fp8 transpose buffer row stride (16B-aligned)

// ---------------- async global->LDS (16B per lane) ----------------
__device__ __forceinline__ void async16(const void* g, void* l) {
  __builtin_amdgcn_global_load_lds((__attribute__((address_space(1))) void*)g,
                                   (__attribute__((address_space(3))) void*)l,
                                   16, 0, 0);
}

// stage a 128x32 bf16 tile (row-major, row stride ld elements) into 8KB LDS
__device__ __forceinline__ void stage_tile(const bf16* gsrc, int ld, char* ldst,
                                           int wv, int lane) {
#pragma unroll
  for (int cc = 0; cc < 2; ++cc) {
    int c = wv * 2 + cc;
    int row = c * 16 + (lane >> 2);
    int col = (lane & 3) * 8;
    async16(gsrc + (size_t)row * ld + col, ldst + c * 1024);
  }
}

// stage a 128x32 fp8 tile (row stride ld bytes) into 4KB LDS; wave wv = chunk wv
__device__ __forceinline__ void stage_fp8(const u8* gsrc, int ld, char* ldst,
                                          int wv, int lane) {
  int row = wv * 32 + (lane >> 1);
  int col = (lane & 1) * 16;
  async16(gsrc + (size_t)row * ld + col, ldst + wv * 1024);
}

// one BK=32 bf16 step
__device__ __forceinline__ void mma_step(const char* lA, const char* lB,
                                         f32x4 acc[4][4], int lane, int wr, int wc) {
  bf16x8 af[4], bfr[4];
  int rbase = wr * 64 + (lane & 15);
  int cbase = wc * 64 + (lane & 15);
  int ko = (lane >> 4) * 8;
#pragma unroll
  for (int r = 0; r < 4; ++r)
    af[r] = *(const bf16x8*)(lA + (((rbase + r * 16) * 32) + ko) * 2);
#pragma unroll
  for (int c = 0; c < 4; ++c)
    bfr[c] = *(const bf16x8*)(lB + (((cbase + c * 16) * 32) + ko) * 2);
#pragma unroll
  for (int r = 0; r < 4; ++r)
#pragma unroll
    for (int c = 0; c < 4; ++c)
      acc[r][c] = __builtin_amdgcn_mfma_f32_16x16x32_bf16(af[r], bfr[c], acc[r][c], 0, 0, 0);
}

// one BK=32 fp8 step (A,B tiles 128x32 fp8 row-major)
__device__ __forceinline__ void mma_step_fp8(const char* lA, const char* lB,
                                             f32x4 acc[4][4], int lane, int wr, int wc) {
  long af[4], bfr[4];
  int rbase = wr * 64 + (lane & 15);
  int cbase = wc * 64 + (lane & 15);
  int ko = (lane >> 4) * 8;
#pragma unroll
  for (int r = 0; r < 4; ++r)
    af[r] = *(const long*)(lA + (rbase + r * 16) * 32 + ko);
#pragma unroll
  for (int c = 0; c < 4; ++c)
    bfr[c] = *(const long*)(lB + (cbase + c * 16) * 32 + ko);
#pragma unroll
  for (int r = 0; r < 4; ++r)
#pragma unroll
    for (int c = 0; c < 4; ++c)
      acc[r][c] = __builtin_amdgcn_mfma_f32_16x16x32_fp8_fp8(af[r], bfr[c], acc[r][c], 0, 0, 0);
}

// BK=64 bf16 double-slab K-step
__device__ __forceinline__ void k_step64(const bf16* Ab, int lda, const bf16* Bb, int ldb,
                                         char* smem, f32x4 acc[4][4],
                                         int wv, int lane, int wr, int wc) {
  char* lA0 = smem;
  char* lA1 = smem + 8192;
  char* lB0 = smem + 16384;
  char* lB1 = smem + 24576;
  __syncthreads();
  stage_tile(Ab, lda, lA0, wv, lane);
  stage_tile(Ab + 32, lda, lA1, wv, lane);
  stage_tile(Bb, ldb, lB0, wv, lane);
  stage_tile(Bb + 32, ldb, lB1, wv, lane);
  __builtin_amdgcn_s_waitcnt(0);
  __syncthreads();
  mma_step(lA0, lB0, acc, lane, wr, wc);
  mma_step(lA1, lB1, acc, lane, wr, wc);
}

// pack 4 floats -> 4 fp8(e4m3) in a uint
__device__ __forceinline__ unsigned pack4(float a, float b, float c, float d) {
  int w = 0;
  w = __builtin_amdgcn_cvt_pk_fp8_f32(a, b, w, false);
  w = __builtin_amdgcn_cvt_pk_fp8_f32(c, d, w, true);
  return (unsigned)w;
}

// ---------------- K0: fused prep (dw/cast/zero-neigh) + weight combine ----------------
__global__ void k_pre(const float* __restrict__ node, const float* __restrict__ Wq,
                      const float* __restrict__ bq, bf16* __restrict__ node_bf,
                      float* __restrict__ dw, float* __restrict__ allw,
                      float* __restrict__ neigh,
                      const float* __restrict__ Ws,
                      const float* __restrict__ Wa, const float* __restrict__ Wp,
                      const float* __restrict__ Wap, const float* __restrict__ Wpp,
                      const float* __restrict__ Wa2, const float* __restrict__ Wp2,
                      const float* __restrict__ Wap2, const float* __restrict__ Wpp2,
                      bf16* __restrict__ Wcat4, bf16* __restrict__ Ws_bf) {
  if (blockIdx.x < MM / 4) {
    int lane = threadIdx.x & 63, wv = threadIdx.x >> 6;
    int row = blockIdx.x * 4 + wv;
    const float* nr = node + (size_t)row * DD;
    bf16* nb = node_bf + (size_t)row * DD;
    float s = 0.f;
#pragma unroll
    for (int k = 0; k < DD / 64; ++k) {
      int idx = lane + k * 64;
      float v = nr[idx];
      nb[idx] = (bf16)v;
      s += v * Wq[idx];
    }
#pragma unroll
    for (int off = 32; off; off >>= 1) s += __shfl_down(s, off);
    if (lane == 0) {
      float z = s + bq[0];
      float d = 1.f / (1.f + expf(-z));
      dw[row] = d;
      allw[row] = d;
      neigh[row] = 0.f;
    }
  } else {
    int i = (blockIdx.x - MM / 4) * 256 + threadIdx.x;   // 0..589823
    Ws_bf[i] = (bf16)Ws[i];
    Wcat4[i]           = (bf16)(Wa[i] + Wa2[i]);
    Wcat4[i + WSZ]     = (bf16)(Wp[i] + Wp2[i]);
    Wcat4[i + 2 * WSZ] = (bf16)(Wap[i] + Wap2[i]);
    Wcat4[i + 3 * WSZ] = (bf16)(Wpp[i] + Wpp2[i]);
  }
}

// ---------------- K1: merged graph + proj (independent work, one launch) ----------------
// grid 4096: blockIdx%4==3 -> graph tile (1024), else proj tile (3072), interleaved 3:1.
// graph: g8[b][i][X*256+j] = fp8(g_X)  (NO dw — folded into p8), neigh atomics.
// proj:  p8[b][e][X*256+j] = fp8(dw[b,j] * (node @ WX^T)[b,j,e])
__global__ __launch_bounds__(256) void k_mid(const int* __restrict__ mask,
                                             const int* __restrict__ arg,
                                             const int* __restrict__ pun,
                                             const float* __restrict__ dw,
                                             const bf16* __restrict__ node_bf,
                                             const bf16* __restrict__ Wcat4,
                                             u8* __restrict__ g8,
                                             float* __restrict__ neigh,
                                             u8* __restrict__ p8) {
  __shared__ __align__(16) char smem[32768];
  int tid = threadIdx.x;
  int s = blockIdx.x & 3, g = blockIdx.x >> 2;

  if (s == 3) {
    // ---------- graph tile ----------
    bf16* la = (bf16*)smem;                  // [64][66] bf16 ({0,1} exact)
    bf16* lp = la + 64 * 66;
    float* msk = (float*)(lp + 64 * 66);     // [256]
    int b = g >> 4, it = (g >> 2) & 3, jt = g & 3;
    int i0 = it * 64, j0 = jt * 64;
    msk[tid] = (float)mask[b * NN + tid];
    __syncthreads();
    int ir = tid >> 2, c4 = (tid & 3) * 16;
    int i = i0 + ir;
    float mi = msk[i];
    size_t gb = (size_t)b * NN * NN;
    const int* ap = arg + gb + (size_t)i * NN + j0 + c4;
    const int* pp = pun + gb + (size_t)i * NN + j0 + c4;
    float va[16], vp[16];
    float racc = 0.f;
#pragma unroll
    for (int k = 0; k < 16; ++k) {
      int j = j0 + c4 + k;
      float dd = (i == j) ? 0.f : mi * msk[j];
      float ga = dd * (float)ap[k];
      float gp = dd * (float)pp[k];
      la[ir * 66 + c4 + k] = (bf16)ga;
      lp[ir * 66 + c4 + k] = (bf16)gp;
      va[k] = ga;
      vp[k] = gp;
      racc += ga + gp;
    }
    uint4 oa, op;
#pragma unroll
    for (int q = 0; q < 4; ++q) {
      (&oa.x)[q] = pack4(va[q*4], va[q*4+1], va[q*4+2], va[q*4+3]);
      (&op.x)[q] = pack4(vp[q*4], vp[q*4+1], vp[q*4+2], vp[q*4+3]);
    }
    *(uint4*)(g8 + (size_t)(b * NN + i) * KP + 0 * NN + j0 + c4) = oa;
    *(uint4*)(g8 + (size_t)(b * NN + i) * KP + 1 * NN + j0 + c4) = op;
    racc += __shfl_xor(racc, 1);
    racc += __shfl_xor(racc, 2);
    if ((tid & 3) == 0) atomicAdd(&neigh[b * NN + i], racc);
    __syncthreads();
    int jr = ir, ic4 = c4;
    float cacc = 0.f;
#pragma unroll
    for (int k = 0; k < 16; ++k) {
      float ga = (float)la[(ic4 + k) * 66 + jr];
      float gp = (float)lp[(ic4 + k) * 66 + jr];
      va[k] = ga;
      vp[k] = gp;
      cacc += ga + gp;
    }
#pragma unroll
    for (int q = 0; q < 4; ++q) {
      (&oa.x)[q] = pack4(va[q*4], va[q*4+1], va[q*4+2], va[q*4+3]);
      (&op.x)[q] = pack4(vp[q*4], vp[q*4+1], vp[q*4+2], vp[q*4+3]);
    }
    *(uint4*)(g8 + (size_t)(b * NN + j0 + jr) * KP + 2 * NN + i0 + ic4) = oa;
    *(uint4*)(g8 + (size_t)(b * NN + j0 + jr) * KP + 3 * NN + i0 + ic4) = op;
    cacc += __shfl_xor(cacc, 1);
    cacc += __shfl_xor(cacc, 2);
    if ((tid & 3) == 0) atomicAdd(&neigh[b * NN + j0 + jr], cacc);
    return;
  }

  // ---------- proj tile (bf16 MFMA, fp8 output, dw folded into epilogue) ----------
  int p = g * 3 + s;                 // 0..3071
  int m0 = (p % 128) * 128;          // node rows (b,j)
  int n0 = (p / 128) * 128;          // (X,e) rows; 128 | 768 so X fixed per tile
  int lane = tid & 63, wv = tid >> 6, wr = wv >> 1, wc = wv & 1;
  const bf16* Ab = node_bf + (size_t)m0 * DD;
  const bf16* Bb = Wcat4 + (size_t)n0 * DD;
  f32x4 z = {0.f, 0.f, 0.f, 0.f};
  f32x4 acc[4][4];
#pragma unroll
  for (int r = 0; r < 4; ++r)
#pragma unroll
    for (int c = 0; c < 4; ++c) acc[r][c] = z;
  for (int k0 = 0; k0 < DD; k0 += 64)
    k_step64(Ab + k0, DD, Bb + k0, DD, smem, acc, wv, lane, wr, wc);
  __syncthreads();                         // staging slabs dead, reuse as transpose buf
  int b = m0 >> 8, j0 = m0 & 255;
  int X = n0 / DD, e0 = n0 - X * DD;
  u8* tb = (u8*)smem;                      // [128][TL] fp8
  // write C^T: n-row, m-col; 4 consecutive m(=j) pack into one uint; scale by dw[b,j]
#pragma unroll
  for (int r = 0; r < 4; ++r) {
    int mb = wr * 64 + r * 16 + ((lane >> 4) << 2);
    f32x4 dv = *(const f32x4*)(dw + b * NN + j0 + mb);
#pragma unroll
    for (int c = 0; c < 4; ++c) {
      int n = wc * 64 + c * 16 + (lane & 15);
      *(unsigned*)(tb + n * TL + mb) =
          pack4(acc[r][c][0] * dv[0], acc[r][c][1] * dv[1],
                acc[r][c][2] * dv[2], acc[r][c][3] * dv[3]);
    }
  }
  __syncthreads();
  u8* obase = p8 + ((size_t)b * DD + e0) * KP + X * NN + j0;
#pragma unroll
  for (int t = 0; t < 4; ++t) {
    int row = t * 32 + (tid >> 3);         // e offset 0..127
    int col = (tid & 7) * 16;              // j offset
    uint4 v = *(const uint4*)(tb + row * TL + col);
    *(uint4*)(obase + (size_t)row * KP + col) = v;
  }
}

// ---------------- K2: out = relu(rdenom*(g8 @ p8) + node @ Ws^T + bs) ----------------
// XCD swizzle: all 12 blocks of one b share blockIdx%8 (-> same XCD under RR dispatch).
__global__ __launch_bounds__(256) void k_agg(const u8* __restrict__ g8,
                                             const u8* __restrict__ p8,
                                             const bf16* __restrict__ node_bf,
                                             const bf16* __restrict__ Ws_bf,
                                             const float* __restrict__ neigh,
                                             const float* __restrict__ bs,
                                             float* __restrict__ out) {
  __shared__ __align__(16) char smem[32768];
  int tid = threadIdx.x, lane = tid & 63, wv = tid >> 6, wr = wv >> 1, wc = wv & 1;
  int l = blockIdx.x;
  int xcd = l & 7, idx = l >> 3;
  int b = (idx / 12) * 8 + xcd;
  int t = idx % 12;
  int i0 = (t / 6) * 128, e0 = (t % 6) * 128;
  f32x4 z = {0.f, 0.f, 0.f, 0.f};
  f32x4 acc[4][4];
#pragma unroll
  for (int r = 0; r < 4; ++r)
#pragma unroll
    for (int c = 0; c < 4; ++c) acc[r][c] = z;
  // phase 1: agg_raw = g8 @ p8_b (K = 1024, fp8, BK=128)
  const u8* Ab = g8 + (size_t)(b * NN + i0) * KP;
  const u8* Bb = p8 + ((size_t)b * DD + e0) * KP;
  for (int k0 = 0; k0 < KP; k0 += 128) {
    __syncthreads();
#pragma unroll
    for (int ss = 0; ss < 4; ++ss) {
      stage_fp8(Ab + k0 + ss * 32, KP, smem + ss * 4096, wv, lane);
      stage_fp8(Bb + k0 + ss * 32, KP, smem + 16384 + ss * 4096, wv, lane);
    }
    __builtin_amdgcn_s_waitcnt(0);
    __syncthreads();
#pragma unroll
    for (int ss = 0; ss < 4; ++ss)
      mma_step_fp8(smem + ss * 4096, smem + 16384 + ss * 4096, acc, lane, wr, wc);
  }
  // inter-phase: scale by 1/denom
  int rowb = i0 + wr * 64 + (lane >> 4) * 4;
#pragma unroll
  for (int r = 0; r < 4; ++r)
#pragma unroll
    for (int q = 0; q < 4; ++q) {
      float rd = 1.f / fmaxf(neigh[b * NN + rowb + r * 16 + q], 1.f);
#pragma unroll
      for (int c = 0; c < 4; ++c) acc[r][c][q] *= rd;
    }
  // phase 2: + node @ Ws^T (K = 768, bf16 — fp8 here would blow the absmax tail)
  const bf16* Ab2 = node_bf + (size_t)(b * NN + i0) * DD;
  const bf16* Bb2 = Ws_bf + (size_t)e0 * DD;
  for (int k0 = 0; k0 < DD; k0 += 64)
    k_step64(Ab2 + k0, DD, Bb2 + k0, DD, smem, acc, wv, lane, wr, wc);
  // epilogue: relu(acc + bs) -> out (written exactly once)
  int colb = e0 + wc * 64 + (lane & 15);
#pragma unroll
  for (int c = 0; c < 4; ++c) {
    int col = colb + c * 16;
    float bv = bs[col];
#pragma unroll
    for (int r = 0; r < 4; ++r)
#pragma unroll
      for (int q = 0; q < 4; ++q) {
        int m = b * NN + rowb + r * 16 + q;
        out[(size_t)m * DD + col] = fmaxf(acc[r][c][q] + bv, 0.f);
      }
  }
}

// ---------------- launch ----------------
extern "C" void kernel_launch(void* const* d_in, const int* in_sizes, int n_in,
                              void* d_out, int out_size, void* d_ws, size_t ws_size,
                              hipStream_t stream) {
  const float* node = (const float*)d_in[0];
  const int* mask   = (const int*)d_in[1];
  const int* arg    = (const int*)d_in[2];
  const int* pun    = (const int*)d_in[3];
  const float* Wq   = (const float*)d_in[4];
  const float* bq   = (const float*)d_in[5];
  const float* Ws   = (const float*)d_in[6];
  const float* bs   = (const float*)d_in[7];
  const float* Wa   = (const float*)d_in[8];
  const float* Wp   = (const float*)d_in[9];
  const float* Wap  = (const float*)d_in[10];
  const float* Wpp  = (const float*)d_in[11];
  const float* Wa2  = (const float*)d_in[12];
  const float* Wp2  = (const float*)d_in[13];
  const float* Wap2 = (const float*)d_in[14];
  const float* Wpp2 = (const float*)d_in[15];

  float* out  = (float*)d_out;              // node: 16384*768 fp32
  float* allw = out + (size_t)MM * DD;      // all_weight: 16384 fp32

  char* ws = (char*)d_ws;
  bf16* node_bf = (bf16*)ws;                    // 25,165,824 B
  float* dw     = (float*)(ws + 25165824);      //     65,536 B
  float* neigh  = (float*)(ws + 25231360);      //     65,536 B
  bf16* Wcat4   = (bf16*)(ws + 25296896);       //  4,718,592 B  bf16 combined rel weights
  bf16* Ws_bf   = (bf16*)(ws + 30015488);       //  1,179,648 B
  u8*   g8      = (u8*)(ws + 31195136);         // 16,777,216 B  [b][i][X*256+j] fp8
  u8*   p8      = (u8*)(ws + 47972352);         // 50,331,648 B  [b][e][X*256+j] fp8
  (void)ws_size; (void)in_sizes; (void)n_in; (void)out_size;

  k_pre<<<MM / 4 + WSZ / 256, 256, 0, stream>>>(node, Wq, bq, node_bf, dw, allw,
                                                neigh, Ws, Wa, Wp, Wap, Wpp,
                                                Wa2, Wp2, Wap2, Wpp2, Wcat4, Ws_bf);
  k_mid<<<4096, 256, 0, stream>>>(mask, arg, pun, dw, node_bf, Wcat4, g8, neigh, p8);
  k_agg<<<12 * BB, 256, 0, stream>>>(g8, p8, node_bf, Ws_bf, neigh, bs, out);
}

// Round 8
// 329.457 us; speedup vs baseline: 1.1037x; 1.1037x over previous
//
#include <hip/hip_runtime.h>
#include <hip/hip_bf16.h>
#include <math.h>

typedef __bf16 bf16;
typedef unsigned char u8;
typedef unsigned long long ull;
typedef __bf16 bf16x8 __attribute__((ext_vector_type(8)));
typedef float f32x4 __attribute__((ext_vector_type(4)));

#define BB 64
#define NN 256
#define DD 768
#define MM (BB*NN)           // 16384
#define KP 1024              // agg phase-1 K (4 relations * 256)
#define WSZ (DD*DD)          // 589824
#define TL 144               // fp8 transpose buffer row stride (16B-aligned)

// fp8 tiled layout: [tile][koq(4)][m(128)] -> 4096B tiles, koq = (K%32)/8
// g8 tile id: (b*2 + i/128)*32 + K/32          (16 MB total)
// p8 tile id: (b*6 + e/128)*32 + K/32          (50 MB total)

// ---------------- async global->LDS (16B per lane) ----------------
__device__ __forceinline__ void async16(const void* g, void* l) {
  __builtin_amdgcn_global_load_lds((__attribute__((address_space(1))) void*)g,
                                   (__attribute__((address_space(3))) void*)l,
                                   16, 0, 0);
}

// stage a 128x32 bf16 tile (row-major, row stride ld elements) into 8KB LDS
__device__ __forceinline__ void stage_tile(const bf16* gsrc, int ld, char* ldst,
                                           int wv, int lane) {
#pragma unroll
  for (int cc = 0; cc < 2; ++cc) {
    int c = wv * 2 + cc;
    int row = c * 16 + (lane >> 2);
    int col = (lane & 3) * 8;
    async16(gsrc + (size_t)row * ld + col, ldst + c * 1024);
  }
}

// one BK=32 bf16 step
__device__ __forceinline__ void mma_step(const char* lA, const char* lB,
                                         f32x4 acc[4][4], int lane, int wr, int wc) {
  bf16x8 af[4], bfr[4];
  int rbase = wr * 64 + (lane & 15);
  int cbase = wc * 64 + (lane & 15);
  int ko = (lane >> 4) * 8;
#pragma unroll
  for (int r = 0; r < 4; ++r)
    af[r] = *(const bf16x8*)(lA + (((rbase + r * 16) * 32) + ko) * 2);
#pragma unroll
  for (int c = 0; c < 4; ++c)
    bfr[c] = *(const bf16x8*)(lB + (((cbase + c * 16) * 32) + ko) * 2);
#pragma unroll
  for (int r = 0; r < 4; ++r)
#pragma unroll
    for (int c = 0; c < 4; ++c)
      acc[r][c] = __builtin_amdgcn_mfma_f32_16x16x32_bf16(af[r], bfr[c], acc[r][c], 0, 0, 0);
}

// one BK=32 fp8 step on a K-major-8B tiled slab: conflict-free b64 reads
__device__ __forceinline__ void mma_step_fp8t(const char* lA, const char* lB,
                                              f32x4 acc[4][4], int lane, int wr, int wc) {
  long af[4], bfr[4];
  int koq = (lane >> 4) * 1024;
  int mA = (wr * 64 + (lane & 15)) * 8;
  int mB = (wc * 64 + (lane & 15)) * 8;
#pragma unroll
  for (int r = 0; r < 4; ++r)
    af[r] = *(const long*)(lA + koq + mA + r * 128);
#pragma unroll
  for (int c = 0; c < 4; ++c)
    bfr[c] = *(const long*)(lB + koq + mB + c * 128);
#pragma unroll
  for (int r = 0; r < 4; ++r)
#pragma unroll
    for (int c = 0; c < 4; ++c)
      acc[r][c] = __builtin_amdgcn_mfma_f32_16x16x32_fp8_fp8(af[r], bfr[c], acc[r][c], 0, 0, 0);
}

// BK=64 bf16 double-slab K-step
__device__ __forceinline__ void k_step64(const bf16* Ab, int lda, const bf16* Bb, int ldb,
                                         char* smem, f32x4 acc[4][4],
                                         int wv, int lane, int wr, int wc) {
  char* lA0 = smem;
  char* lA1 = smem + 8192;
  char* lB0 = smem + 16384;
  char* lB1 = smem + 24576;
  __syncthreads();
  stage_tile(Ab, lda, lA0, wv, lane);
  stage_tile(Ab + 32, lda, lA1, wv, lane);
  stage_tile(Bb, ldb, lB0, wv, lane);
  stage_tile(Bb + 32, ldb, lB1, wv, lane);
  __builtin_amdgcn_s_waitcnt(0);
  __syncthreads();
  mma_step(lA0, lB0, acc, lane, wr, wc);
  mma_step(lA1, lB1, acc, lane, wr, wc);
}

// pack 4 floats -> 4 fp8(e4m3) in a uint
__device__ __forceinline__ unsigned pack4(float a, float b, float c, float d) {
  int w = 0;
  w = __builtin_amdgcn_cvt_pk_fp8_f32(a, b, w, false);
  w = __builtin_amdgcn_cvt_pk_fp8_f32(c, d, w, true);
  return (unsigned)w;
}

// ---------------- K0: fused prep (dw/cast/zero-neigh) + weight combine ----------------
__global__ void k_pre(const float* __restrict__ node, const float* __restrict__ Wq,
                      const float* __restrict__ bq, bf16* __restrict__ node_bf,
                      float* __restrict__ dw, float* __restrict__ allw,
                      float* __restrict__ neigh,
                      const float* __restrict__ Ws,
                      const float* __restrict__ Wa, const float* __restrict__ Wp,
                      const float* __restrict__ Wap, const float* __restrict__ Wpp,
                      const float* __restrict__ Wa2, const float* __restrict__ Wp2,
                      const float* __restrict__ Wap2, const float* __restrict__ Wpp2,
                      bf16* __restrict__ Wcat4, bf16* __restrict__ Ws_bf) {
  if (blockIdx.x < MM / 4) {
    int lane = threadIdx.x & 63, wv = threadIdx.x >> 6;
    int row = blockIdx.x * 4 + wv;
    const float* nr = node + (size_t)row * DD;
    bf16* nb = node_bf + (size_t)row * DD;
    float s = 0.f;
#pragma unroll
    for (int k = 0; k < DD / 64; ++k) {
      int idx = lane + k * 64;
      float v = nr[idx];
      nb[idx] = (bf16)v;
      s += v * Wq[idx];
    }
#pragma unroll
    for (int off = 32; off; off >>= 1) s += __shfl_down(s, off);
    if (lane == 0) {
      float z = s + bq[0];
      float d = 1.f / (1.f + expf(-z));
      dw[row] = d;
      allw[row] = d;
      neigh[row] = 0.f;
    }
  } else {
    int i = (blockIdx.x - MM / 4) * 256 + threadIdx.x;   // 0..589823
    Ws_bf[i] = (bf16)Ws[i];
    Wcat4[i]           = (bf16)(Wa[i] + Wa2[i]);
    Wcat4[i + WSZ]     = (bf16)(Wp[i] + Wp2[i]);
    Wcat4[i + 2 * WSZ] = (bf16)(Wap[i] + Wap2[i]);
    Wcat4[i + 3 * WSZ] = (bf16)(Wpp[i] + Wpp2[i]);
  }
}

// store a 16B (two 8B koq pieces) value into the tiled fp8 layout
__device__ __forceinline__ void store_tiled(u8* base, int tile, int kin, int m, uint4 v) {
  size_t o = (size_t)tile * 4096 + (size_t)((kin >> 3) * 1024 + m * 8);
  *(ull*)(base + o)        = ((ull)v.y << 32) | v.x;
  *(ull*)(base + o + 1024) = ((ull)v.w << 32) | v.z;
}

// ---------------- K0b: g8 tiled = fp8(dw_src * g_X), neigh (atomic) ----------------
__global__ void k_graph(const int* __restrict__ mask, const int* __restrict__ arg,
                        const int* __restrict__ pun, const float* __restrict__ dw,
                        u8* __restrict__ g8, float* __restrict__ neigh) {
  __shared__ float la[64][65];
  __shared__ float lp[64][65];
  __shared__ float msk[256];
  __shared__ float dwv[256];
  int tid = threadIdx.x;
  int bi = blockIdx.x;
  int b = bi >> 4, it = (bi >> 2) & 3, jt = bi & 3;
  int i0 = it * 64, j0 = jt * 64;
  msk[tid] = (float)mask[b * NN + tid];
  dwv[tid] = dw[b * NN + tid];
  __syncthreads();
  int ir = tid >> 2, c4 = (tid & 3) * 16;
  int i = i0 + ir;
  float mi = msk[i];
  size_t gb = (size_t)b * NN * NN;
  const int* ap = arg + gb + (size_t)i * NN + j0 + c4;
  const int* pp = pun + gb + (size_t)i * NN + j0 + c4;
  float va[16], vp[16];
  float racc = 0.f;
#pragma unroll
  for (int k = 0; k < 16; ++k) {
    int j = j0 + c4 + k;
    float dd = (i == j) ? 0.f : mi * msk[j];
    float ga = dd * (float)ap[k];
    float gp = dd * (float)pp[k];
    la[ir][c4 + k] = ga;
    lp[ir][c4 + k] = gp;
    float w = dwv[j];
    va[k] = w * ga;
    vp[k] = w * gp;
    racc += ga + gp;
  }
  uint4 oa, op;
#pragma unroll
  for (int g = 0; g < 4; ++g) {
    (&oa.x)[g] = pack4(va[g*4], va[g*4+1], va[g*4+2], va[g*4+3]);
    (&op.x)[g] = pack4(vp[g*4], vp[g*4+1], vp[g*4+2], vp[g*4+3]);
  }
  {
    int tR = (b * 2 + (i >> 7)) * 32;
    int K0 = j0 + c4;                       // X=0 K index; X=1 adds 256 (+8 tiles)
    store_tiled(g8, tR + (K0 >> 5),       K0 & 31, i & 127, oa);
    store_tiled(g8, tR + 8 + (K0 >> 5),   K0 & 31, i & 127, op);
  }
  racc += __shfl_xor(racc, 1);
  racc += __shfl_xor(racc, 2);
  if ((tid & 3) == 0) atomicAdd(&neigh[b * NN + i], racc);
  __syncthreads();
  int jr = ir, ic4 = c4;
  float cacc = 0.f;
#pragma unroll
  for (int k = 0; k < 16; ++k) {
    float ga = la[ic4 + k][jr];
    float gp = lp[ic4 + k][jr];
    float w = dwv[i0 + ic4 + k];
    va[k] = w * ga;
    vp[k] = w * gp;
    cacc += ga + gp;
  }
#pragma unroll
  for (int g = 0; g < 4; ++g) {
    (&oa.x)[g] = pack4(va[g*4], va[g*4+1], va[g*4+2], va[g*4+3]);
    (&op.x)[g] = pack4(vp[g*4], vp[g*4+1], vp[g*4+2], vp[g*4+3]);
  }
  {
    int row = j0 + jr;
    int tR = (b * 2 + (row >> 7)) * 32;
    int K2 = i0 + ic4;                      // X=2 base 512 (+16 tiles); X=3 +24
    store_tiled(g8, tR + 16 + (K2 >> 5),  K2 & 31, row & 127, oa);
    store_tiled(g8, tR + 24 + (K2 >> 5),  K2 & 31, row & 127, op);
  }
  cacc += __shfl_xor(cacc, 1);
  cacc += __shfl_xor(cacc, 2);
  if ((tid & 3) == 0) atomicAdd(&neigh[b * NN + j0 + jr], cacc);
}

// ---------------- K1: p8 tiled = fp8((node @ WX^T)^T)  (bf16 MFMA) ----------------
__global__ __launch_bounds__(256) void k_proj(const bf16* __restrict__ node_bf,
                                              const bf16* __restrict__ Wcat4,
                                              u8* __restrict__ p8) {
  __shared__ __align__(16) char smem[32768];
  int tid = threadIdx.x, lane = tid & 63, wv = tid >> 6, wr = wv >> 1, wc = wv & 1;
  int m0 = blockIdx.x * 128;      // 16384 node rows (b,j)
  int n0 = blockIdx.y * 128;      // 3072 = (X,e) rows; 128 | 768 so X fixed per tile
  const bf16* Ab = node_bf + (size_t)m0 * DD;
  const bf16* Bb = Wcat4 + (size_t)n0 * DD;
  f32x4 z = {0.f, 0.f, 0.f, 0.f};
  f32x4 acc[4][4];
#pragma unroll
  for (int r = 0; r < 4; ++r)
#pragma unroll
    for (int c = 0; c < 4; ++c) acc[r][c] = z;
  for (int k0 = 0; k0 < DD; k0 += 64)
    k_step64(Ab + k0, DD, Bb + k0, DD, smem, acc, wv, lane, wr, wc);
  __syncthreads();                         // staging slabs dead, reuse as transpose buf
  int b = m0 >> 8, j0 = m0 & 255;
  int X = n0 / DD, e0 = n0 - X * DD;
  u8* tb = (u8*)smem;                      // [128][TL] fp8
  // write C^T: n-row, m-col; 4 consecutive m(=j) pack into one uint
#pragma unroll
  for (int r = 0; r < 4; ++r)
#pragma unroll
    for (int c = 0; c < 4; ++c) {
      int n = wc * 64 + c * 16 + (lane & 15);
      int m = wr * 64 + r * 16 + ((lane >> 4) << 2);
      *(unsigned*)(tb + n * TL + m) =
          pack4(acc[r][c][0], acc[r][c][1], acc[r][c][2], acc[r][c][3]);
    }
  __syncthreads();
  int tR = (b * 6 + (e0 >> 7)) * 32 + X * 8;
#pragma unroll
  for (int t = 0; t < 4; ++t) {
    int row = t * 32 + (tid >> 3);         // e offset 0..127
    int col = (tid & 7) * 16;              // j offset
    uint4 v = *(const uint4*)(tb + row * TL + col);
    int K = j0 + col;                      // K within relation X handled by tR
    store_tiled(p8, tR + (K >> 5), K & 31, row, v);
  }
}

// ---------------- K2: out = relu(rdenom*(g8 @ p8) + node @ Ws^T + bs) ----------------
// XCD swizzle: all 12 blocks of one b share blockIdx%8 (-> same XCD under RR dispatch).
__global__ __launch_bounds__(256) void k_agg(const u8* __restrict__ g8,
                                             const u8* __restrict__ p8,
                                             const bf16* __restrict__ node_bf,
                                             const bf16* __restrict__ Ws_bf,
                                             const float* __restrict__ neigh,
                                             const float* __restrict__ bs,
                                             float* __restrict__ out) {
  __shared__ __align__(16) char smem[32768];
  int tid = threadIdx.x, lane = tid & 63, wv = tid >> 6, wr = wv >> 1, wc = wv & 1;
  int l = blockIdx.x;
  int xcd = l & 7, idx = l >> 3;
  int b = (idx / 12) * 8 + xcd;
  int t = idx % 12;
  int i0 = (t / 6) * 128, e0 = (t % 6) * 128;
  f32x4 z = {0.f, 0.f, 0.f, 0.f};
  f32x4 acc[4][4];
#pragma unroll
  for (int r = 0; r < 4; ++r)
#pragma unroll
    for (int c = 0; c < 4; ++c) acc[r][c] = z;
  // phase 1: agg_raw = g8 @ p8_b (K = 1024, fp8 tiled, BK=128, conflict-free)
  const u8* At = g8 + (size_t)((b * 2 + (i0 >> 7)) * 32) * 4096;
  const u8* Bt = p8 + (size_t)((b * 6 + (e0 >> 7)) * 32) * 4096;
  int lsoff = wv * 1024;
  int goff = lsoff + lane * 16;
  for (int k0 = 0; k0 < KP; k0 += 128) {
    __syncthreads();
#pragma unroll
    for (int s = 0; s < 4; ++s) {
      size_t toff = (size_t)((k0 >> 5) + s) * 4096 + goff;
      async16(At + toff, smem + s * 4096 + lsoff);
      async16(Bt + toff, smem + 16384 + s * 4096 + lsoff);
    }
    __builtin_amdgcn_s_waitcnt(0);
    __syncthreads();
#pragma unroll
    for (int s = 0; s < 4; ++s)
      mma_step_fp8t(smem + s * 4096, smem + 16384 + s * 4096, acc, lane, wr, wc);
  }
  // inter-phase: scale by 1/denom
  int rowb = i0 + wr * 64 + (lane >> 4) * 4;
#pragma unroll
  for (int r = 0; r < 4; ++r)
#pragma unroll
    for (int q = 0; q < 4; ++q) {
      float rd = 1.f / fmaxf(neigh[b * NN + rowb + r * 16 + q], 1.f);
#pragma unroll
      for (int c = 0; c < 4; ++c) acc[r][c][q] *= rd;
    }
  // phase 2: + node @ Ws^T (K = 768, bf16 — fp8 here would blow the absmax tail)
  const bf16* Ab2 = node_bf + (size_t)(b * NN + i0) * DD;
  const bf16* Bb2 = Ws_bf + (size_t)e0 * DD;
  for (int k0 = 0; k0 < DD; k0 += 64)
    k_step64(Ab2 + k0, DD, Bb2 + k0, DD, smem, acc, wv, lane, wr, wc);
  // epilogue: relu(acc + bs) -> out (written exactly once)
  int colb = e0 + wc * 64 + (lane & 15);
#pragma unroll
  for (int c = 0; c < 4; ++c) {
    int col = colb + c * 16;
    float bv = bs[col];
#pragma unroll
    for (int r = 0; r < 4; ++r)
#pragma unroll
      for (int q = 0; q < 4; ++q) {
        int m = b * NN + rowb + r * 16 + q;
        out[(size_t)m * DD + col] = fmaxf(acc[r][c][q] + bv, 0.f);
      }
  }
}

// ---------------- launch ----------------
extern "C" void kernel_launch(void* const* d_in, const int* in_sizes, int n_in,
                              void* d_out, int out_size, void* d_ws, size_t ws_size,
                              hipStream_t stream) {
  const float* node = (const float*)d_in[0];
  const int* mask   = (const int*)d_in[1];
  const int* arg    = (const int*)d_in[2];
  const int* pun    = (const int*)d_in[3];
  const float* Wq   = (const float*)d_in[4];
  const float* bq   = (const float*)d_in[5];
  const float* Ws   = (const float*)d_in[6];
  const float* bs   = (const float*)d_in[7];
  const float* Wa   = (const float*)d_in[8];
  const float* Wp   = (const float*)d_in[9];
  const float* Wap  = (const float*)d_in[10];
  const float* Wpp  = (const float*)d_in[11];
  const float* Wa2  = (const float*)d_in[12];
  const float* Wp2  = (const float*)d_in[13];
  const float* Wap2 = (const float*)d_in[14];
  const float* Wpp2 = (const float*)d_in[15];

  float* out  = (float*)d_out;              // node: 16384*768 fp32
  float* allw = out + (size_t)MM * DD;      // all_weight: 16384 fp32

  char* ws = (char*)d_ws;
  bf16* node_bf = (bf16*)ws;                    // 25,165,824 B
  float* dw     = (float*)(ws + 25165824);      //     65,536 B
  float* neigh  = (float*)(ws + 25231360);      //     65,536 B
  bf16* Wcat4   = (bf16*)(ws + 25296896);       //  4,718,592 B  bf16 combined rel weights
  bf16* Ws_bf   = (bf16*)(ws + 30015488);       //  1,179,648 B
  u8*   g8      = (u8*)(ws + 31195136);         // 16,777,216 B  fp8 tiled
  u8*   p8      = (u8*)(ws + 47972352);         // 50,331,648 B  fp8 tiled
  (void)ws_size; (void)in_sizes; (void)n_in; (void)out_size;

  k_pre<<<MM / 4 + WSZ / 256, 256, 0, stream>>>(node, Wq, bq, node_bf, dw, allw,
                                                neigh, Ws, Wa, Wp, Wap, Wpp,
                                                Wa2, Wp2, Wap2, Wpp2, Wcat4, Ws_bf);
  k_graph<<<BB * 16, 256, 0, stream>>>(mask, arg, pun, dw, g8, neigh);
  k_proj<<<dim3(128, 24), 256, 0, stream>>>(node_bf, Wcat4, p8);
  k_agg<<<12 * BB, 256, 0, stream>>>(g8, p8, node_bf, Ws_bf, neigh, bs, out);
}